// Round 11
// baseline (3073.923 us; speedup 1.0000x reference)
//
#include <hip/hip_runtime.h>
#include <cstddef>

// Sparse 3D CNN. R18: small-kernel consolidation. R17 (2991us) confirmed
// pool re-reads were HBM-bound; conv32m CLOSED at ~376us c2 (6 falsified
// structural attempts). Non-conv32m ~1.9ms >> ~0.7ms BW-model => launch/
// latency overhead of 29 small dispatches dominates. R18: (a) kd_fused2 --
// two chained dilation stages per kernel via max-filter composition (6 LDS
// passes, ping-pong sA/sB <=44.5KB, writes BOTH stage outputs; bit-exact:
// max associative, masks>=0, zero-pad only feeds clipped outputs): 10->5
// launches, intermediate round-trips gone. (b) c1 bounds(256,2)->(256,4)
// isolated. (c) k_repack_all folds wr1/wr7 into the mfma-table launch.
// (d) x0+m0 memsets merged. Launches 35->27.
// R17: pool_zw z-walk. R15: LDS dilations. R14: NINF sentinel + maskless
// pools + fused pool_yx. R13: conv32m tiles c3(8,8,4) c4(4,16,4) c6(8,4,8).
// Chain: 50,60,65 -> c1 47,57,62 -> c2 44,54,59 -> p1 40,50,55 -> c3 37,47,52
// -> c4 34,44,49 -> p2 30,40,45 -> c5 27,37,42 -> c6 24,34,39 -> c7 21,31,36
// -> p3 17,27,32 ; flatten 14688 -> FC 1000 -> 1000 -> 1

#define NEGSLOPE 0.01f
#define NINF (-3.0e38f)

// c1/c7 tile geometry: 4x4x16 out, 7x7x19 halo
#define TZ 4
#define TY 4
#define TXT 16
#define IZ 7
#define IY 7
#define IX 19
#define NV (IZ*IY*IX)    // 931 voxels

#define PCZ 10           // pool z-walk chunk (outputs per thread)

typedef __attribute__((ext_vector_type(8)))  short    short8;    // 8 bf16
typedef __attribute__((ext_vector_type(4)))  unsigned uint4v;
typedef __attribute__((ext_vector_type(16))) float    floatx16;  // 32x32 acc

constexpr int ilog2c(int v) { return v == 1 ? 0 : 1 + ilog2c(v / 2); }

__device__ __forceinline__ float lrelu(float v) { return v >= 0.f ? v : NEGSLOPE * v; }

__device__ __forceinline__ unsigned short f2bf(float f) {
  unsigned b = __float_as_uint(f);
  return (unsigned short)((b + 0x7fffu + ((b >> 16) & 1u)) >> 16);   // RNE
}
__device__ __forceinline__ float bf2f(unsigned short h) {
  return __uint_as_float(((unsigned)h) << 16);
}
__device__ __forceinline__ unsigned splitpair(float a, float b, unsigned& lo) {
  unsigned short ha = f2bf(a), hb = f2bf(b);
  unsigned short la = f2bf(a - bf2f(ha)), lb = f2bf(b - bf2f(hb));
  lo = (unsigned)la | ((unsigned)lb << 16);
  return (unsigned)ha | ((unsigned)hb << 16);
}

__device__ __forceinline__ float4 max4(float4 a, float4 b) {
  float4 r;
  r.x = fmaxf(a.x, b.x); r.y = fmaxf(a.y, b.y);
  r.z = fmaxf(a.z, b.z); r.w = fmaxf(a.w, b.w);
  return r;
}

// load A-frag (8 bf16) from LDS at 40B voxel stride; oct 0 = hi, oct 1 = lo
__device__ __forceinline__ short8 ld_frag(const uint2* s2, int v, int oct) {
  uint2 u0 = s2[v * 5 + oct * 2];
  uint2 u1 = s2[v * 5 + oct * 2 + 1];
  uint4v t; t.x = u0.x; t.y = u0.y; t.z = u1.x; t.w = u1.y;
  return __builtin_bit_cast(short8, t);
}

// ---------------- scatter (last-write-wins), full batch ----------------
__global__ void k_claim(const int* __restrict__ coors, unsigned* __restrict__ claim, int N) {
  int i = blockIdx.x * blockDim.x + threadIdx.x;
  if (i >= N) return;
  int b = coors[4*i], z = coors[4*i+1], y = coors[4*i+2], x = coors[4*i+3];
  int v = ((b*50 + z)*60 + y)*65 + x;
  atomicMax(&claim[v], (unsigned)(i + 1));
}

__global__ void k_scatter(const int* __restrict__ coors, const float* __restrict__ feat,
                          const unsigned* __restrict__ claim,
                          float* __restrict__ x0, float* __restrict__ m0, int N) {
  int i = blockIdx.x * blockDim.x + threadIdx.x;
  if (i >= N) return;
  int b = coors[4*i], z = coors[4*i+1], y = coors[4*i+2], x = coors[4*i+3];
  int v = ((b*50 + z)*60 + y)*65 + x;
  m0[v] = 1.f;
  if (claim[v] == (unsigned)(i + 1)) x0[v] = feat[i];
}

// ---------------- unified weight repack: 5 MFMA tables + wr1 + wr7 ----------------
// layer 0..4: conv32 bf16 hi/lo B-frag tables (512 KB each, contiguous).
// layer 5: w1 (CI=1,CO=32) -> wr1[k*32+co]. layer 6: w7 (CI=32,CO=1) -> wr7[k*32+ci].
__global__ void k_repack_all(const float* __restrict__ wA, const float* __restrict__ wB,
                             const float* __restrict__ wC, const float* __restrict__ wD,
                             const float* __restrict__ wE,
                             const float* __restrict__ w1, const float* __restrict__ w7,
                             unsigned short* __restrict__ tbl0,
                             float* __restrict__ wr1, float* __restrict__ wr7) {
  int layer = blockIdx.y;
  int i = blockIdx.x * blockDim.x + threadIdx.x;
  if (layer >= 5) {
    if (i < 2048) {
      int k = i & 63;
      if (layer == 5) { int co = i >> 6; wr1[k * 32 + co] = w1[i]; }
      else           { int ci = (i >> 6) & 31; wr7[k * 32 + ci] = w7[i]; }
    }
    return;
  }
  const float* w = layer == 0 ? wA : layer == 1 ? wB : layer == 2 ? wC
                 : layer == 3 ? wD : wE;
  unsigned short* tbl = tbl0 + (size_t)layer * 262144;   // 512 KB / 2B
  if (i >= 64*4*2*64) return;
  int lane = i & 63; int t = i >> 6;
  int pack = t & 1; t >>= 1;
  int pass = t & 3; int tap = t >> 2;
  int co = lane & 31; int oct = lane >> 5;
#pragma unroll
  for (int j = 0; j < 8; ++j) {
    int k = oct * 8 + j;
    int ci = pass * 8 + (k & 7);
    int part = ((k >> 3) ^ pack) & 1;
    float wv = w[((co * 32 + ci) << 6) + tap];
    unsigned short wh = f2bf(wv);
    unsigned short r = part ? f2bf(wv - bf2f(wh)) : wh;
    tbl[(size_t)i * 8 + j] = r;
  }
}

// ---------------- two-stage fused separable mask dilation ----------------
// Computes out1 = dilate_K1(in) AND out2 = dilate_K2(out1) in one kernel.
// Tile (4,8,32) on out2; stage-1 region H1 = tile+K2-1; input region H0 =
// H1+K1-1. Six LDS passes ping-pong sA/sB; out1 written from pass 3
// (duplicate identical writes across overlapping tiles are benign).
// Zero-pad only feeds outputs clipped by bounds (dims are exact: Zi=Zo+K-1).
template<int K1, int K2>
__global__ __launch_bounds__(256, 2)
void kd_fused2(const float* __restrict__ in, float* __restrict__ out1,
               float* __restrict__ out2,
               int Z0, int Y0, int X0, int Z1, int Y1, int X1,
               int Z2, int Y2, int X2,
               int tilesZ, int tilesY, int tilesX) {
  constexpr int TDZ = 4, TDY = 8, TDX = 32;
  constexpr int H1Z = TDZ + K2 - 1, H1Y = TDY + K2 - 1, H1X = TDX + K2 - 1;
  constexpr int H0Z = H1Z + K1 - 1, H0Y = H1Y + K1 - 1, H0X = H1X + K1 - 1;
  __shared__ float sA[H0Z * H0Y * H0X];
  __shared__ float sB[H1Z * H0Y * H0X];
  int bid = blockIdx.x;
  int txi = bid % tilesX; bid /= tilesX;
  int tyi = bid % tilesY; bid /= tilesY;
  int tzi = bid % tilesZ; int item = bid / tilesZ;
  const int z0 = tzi * TDZ, y0 = tyi * TDY, x0 = txi * TDX;
  const int tid = threadIdx.x;
  const float* ib = in + (size_t)item * Z0 * Y0 * X0;

  for (int idx = tid; idx < H0Z * H0Y * H0X; idx += 256) {
    int iz = idx / (H0Y * H0X); int r = idx - iz * (H0Y * H0X);
    int iy = r / H0X; int ix = r - iy * H0X;
    int gz = z0 + iz, gy = y0 + iy, gx = x0 + ix;
    float v = 0.f;
    if (gz < Z0 && gy < Y0 && gx < X0) v = ib[((size_t)gz * Y0 + gy) * X0 + gx];
    sA[idx] = v;
  }
  __syncthreads();
  // p1: z-max K1 -> sB (H1Z, H0Y, H0X)
  for (int idx = tid; idx < H1Z * H0Y * H0X; idx += 256) {
    int z = idx / (H0Y * H0X); int r = idx - z * (H0Y * H0X);
    float m = 0.f;
#pragma unroll
    for (int d = 0; d < K1; ++d) m = fmaxf(m, sA[(z + d) * (H0Y * H0X) + r]);
    sB[idx] = m;
  }
  __syncthreads();
  // p2: y-max K1 -> sA (H1Z, H1Y, H0X)
  for (int idx = tid; idx < H1Z * H1Y * H0X; idx += 256) {
    int z = idx / (H1Y * H0X); int r = idx - z * (H1Y * H0X);
    int y = r / H0X; int x = r - y * H0X;
    float m = 0.f;
#pragma unroll
    for (int d = 0; d < K1; ++d) m = fmaxf(m, sB[z * (H0Y * H0X) + (y + d) * H0X + x]);
    sA[idx] = m;
  }
  __syncthreads();
  // p3: x-max K1 -> sB (H1Z, H1Y, H1X) = stage-1; write out1 (clipped)
  for (int idx = tid; idx < H1Z * H1Y * H1X; idx += 256) {
    int z = idx / (H1Y * H1X); int r = idx - z * (H1Y * H1X);
    int y = r / H1X; int x = r - y * H1X;
    float m = 0.f;
#pragma unroll
    for (int d = 0; d < K1; ++d) m = fmaxf(m, sA[z * (H1Y * H0X) + y * H0X + x + d]);
    sB[idx] = m;
    int gz = z0 + z, gy = y0 + y, gx = x0 + x;
    if (gz < Z1 && gy < Y1 && gx < X1)
      out1[(size_t)item * Z1 * Y1 * X1 + ((size_t)gz * Y1 + gy) * X1 + gx] = m;
  }
  __syncthreads();
  // p4: z-max K2 -> sA (TDZ, H1Y, H1X)
  for (int idx = tid; idx < TDZ * H1Y * H1X; idx += 256) {
    int z = idx / (H1Y * H1X); int r = idx - z * (H1Y * H1X);
    float m = 0.f;
#pragma unroll
    for (int d = 0; d < K2; ++d) m = fmaxf(m, sB[(z + d) * (H1Y * H1X) + r]);
    sA[idx] = m;
  }
  __syncthreads();
  // p5: y-max K2 -> sB (TDZ, TDY, H1X)
  for (int idx = tid; idx < TDZ * TDY * H1X; idx += 256) {
    int z = idx / (TDY * H1X); int r = idx - z * (TDY * H1X);
    int y = r / H1X; int x = r - y * H1X;
    float m = 0.f;
#pragma unroll
    for (int d = 0; d < K2; ++d) m = fmaxf(m, sA[z * (H1Y * H1X) + (y + d) * H1X + x]);
    sB[idx] = m;
  }
  __syncthreads();
  // p6: x-max K2 -> out2 (clipped)
  for (int idx = tid; idx < TDZ * TDY * TDX; idx += 256) {
    int z = idx / (TDY * TDX); int r = idx - z * (TDY * TDX);
    int y = r / TDX; int x = r - y * TDX;
    int gz = z0 + z, gy = y0 + y, gx = x0 + x;
    if (gz < Z2 && gy < Y2 && gx < X2) {
      float m = 0.f;
#pragma unroll
      for (int d = 0; d < K2; ++d) m = fmaxf(m, sB[z * (TDY * H1X) + y * H1X + x + d]);
      out2[(size_t)item * Z2 * Y2 * X2 + ((size_t)gz * Y2 + gy) * X2 + gx] = m;
    }
  }
}

// ---------------- MFMA conv 32->32 (templated tile shape, R15 body) ----------------
template<int TZL, int TYL, int TXL, int IZL, int IYL, int IXL, bool POOLOUT>
__global__ __launch_bounds__(256, 4)
void k_conv32m(const float* __restrict__ in, const unsigned short* __restrict__ tbl,
               const float* __restrict__ bias, const float* __restrict__ mo,
               float* __restrict__ out,
               int Zi, int Yi, int Xi, int Zo, int Yo, int Xo,
               int tilesZ, int tilesY, int tilesX) {
  constexpr int NVL = IZL * IYL * IXL;
  constexpr int LXs = ilog2c(TXL);
  constexpr int LYs = ilog2c(TYL);
  __shared__ unsigned sU[NVL * 10];
  const int perIn = Zi * Yi * Xi;
  const int perOut = Zo * Yo * Xo;
  int bid = blockIdx.x;
  int txi = bid % tilesX; bid /= tilesX;
  int tyi = bid % tilesY; bid /= tilesY;
  int tzi = bid % tilesZ; int item = bid / tilesZ;
  const int z0 = tzi * TZL, y0 = tyi * TYL, x0 = txi * TXL;
  const int tid = threadIdx.x;
  const int lane = tid & 63;
  const int col = lane & 31;     // co (B n-index) and A-row m
  const int oct = lane >> 5;
  const int wv  = tid >> 6;      // wave 0..3

  int lvBase0, lvBase1;
  {
    int vt0 = (2*wv + 0)*32 + col;
    int vt1 = (2*wv + 1)*32 + col;
    lvBase0 = ((vt0 >> (LXs+LYs))*IYL + ((vt0 >> LXs) & (TYL-1)))*IXL + (vt0 & (TXL-1));
    lvBase1 = ((vt1 >> (LXs+LYs))*IYL + ((vt1 >> LXs) & (TYL-1)))*IXL + (vt1 & (TXL-1));
  }

  floatx16 acc0, acc1;
#pragma unroll
  for (int r = 0; r < 16; ++r) { acc0[r] = 0.f; acc1[r] = 0.f; }

  const float* inb = in + (size_t)item * perIn * 32;
  const char* tb = (const char*)tbl + lane * 16;
  uint2* s2 = (uint2*)sU;

#pragma unroll 1
  for (int p = 0; p < 4; ++p) {
    __syncthreads();
    for (int idx = tid; idx < NVL; idx += 256) {
      int iz = idx / (IYL * IXL); int r = idx - iz * (IYL * IXL);
      int iy = r / IXL; int ix = r - iy * IXL;
      int gz = z0 + iz, gy = y0 + iy, gx = x0 + ix;
      float4 f0 = make_float4(0.f,0.f,0.f,0.f), f1 = make_float4(0.f,0.f,0.f,0.f);
      if (gz < Zi && gy < Yi && gx < Xi) {
        const float* vp = inb + (size_t)((gz * Yi + gy) * Xi + gx) * 32 + p * 8;
        f0 = *(const float4*)vp;
        f1 = *(const float4*)(vp + 4);
      }
      unsigned l0, l1, l2, l3;
      unsigned h0 = splitpair(f0.x, f0.y, l0);
      unsigned h1 = splitpair(f0.z, f0.w, l1);
      unsigned h2 = splitpair(f1.x, f1.y, l2);
      unsigned h3 = splitpair(f1.z, f1.w, l3);
      s2[idx * 5 + 0] = make_uint2(h0, h1);
      s2[idx * 5 + 1] = make_uint2(h2, h3);
      s2[idx * 5 + 2] = make_uint2(l0, l1);
      s2[idx * 5 + 3] = make_uint2(l2, l3);
    }
    __syncthreads();

    const char* tp = tb + (size_t)p * 2048;
#pragma unroll 2
    for (int tap = 0; tap < 64; ++tap) {
      int kz = tap >> 4, ky = (tap >> 2) & 3, kx = tap & 3;
      int sOff = (kz * IYL + ky) * IXL + kx;
      short8 b0 = *(const short8*)(tp + (size_t)tap * 8192);
      short8 b1 = *(const short8*)(tp + (size_t)tap * 8192 + 1024);
      short8 a0 = ld_frag(s2, lvBase0 + sOff, oct);
      short8 a1 = ld_frag(s2, lvBase1 + sOff, oct);
      acc0 = __builtin_amdgcn_mfma_f32_32x32x16_bf16(a0, b0, acc0, 0, 0, 0);
      acc0 = __builtin_amdgcn_mfma_f32_32x32x16_bf16(a0, b1, acc0, 0, 0, 0);
      acc1 = __builtin_amdgcn_mfma_f32_32x32x16_bf16(a1, b0, acc1, 0, 0, 0);
      acc1 = __builtin_amdgcn_mfma_f32_32x32x16_bf16(a1, b1, acc1, 0, 0, 0);
    }
  }

  // epilogue: C/D layout col=lane&31 (co), row m=(reg&3)+8*(reg>>2)+4*oct
  const float bco = bias[col];
#pragma unroll
  for (int gg = 0; gg < 2; ++gg) {
    int vtb = (2*wv + gg) * 32;
#pragma unroll
    for (int rg = 0; rg < 16; ++rg) {
      int row = (rg & 3) + 8 * (rg >> 2) + 4 * oct;
      int vt = vtb + row;
      int oz = vt >> (LXs+LYs), oy = (vt >> LXs) & (TYL-1), ox = vt & (TXL-1);
      int gz = z0 + oz, gy = y0 + oy, gx = x0 + ox;
      if (gz < Zo && gy < Yo && gx < Xo) {
        int ov = item * perOut + (gz * Yo + gy) * Xo + gx;
        float val = (gg == 0) ? acc0[rg] : acc1[rg];
        bool act = mo[ov] > 0.f;
        float vv = act ? lrelu(val + bco) : (POOLOUT ? NINF : 0.f);
        out[(size_t)ov * 32 + col] = vv;
      }
    }
  }
}

// host-side launcher for a given tile shape
template<int TZL, int TYL, int TXL, int IZL, int IYL, int IXL, bool POOLOUT>
static void launch_conv32(hipStream_t stream,
                          const float* in, const unsigned short* tbl, const float* bias,
                          const float* mo, float* o,
                          int Zi, int Yi, int Xi, int Zo, int Yo, int Xo, int nI) {
  int tz = (Zo + TZL - 1) / TZL, ty = (Yo + TYL - 1) / TYL, tx = (Xo + TXL - 1) / TXL;
  k_conv32m<TZL,TYL,TXL,IZL,IYL,IXL,POOLOUT><<<nI * tz * ty * tx, 256, 0, stream>>>(
      in, tbl, bias, mo, o, Zi, Yi, Xi, Zo, Yo, Xo, tz, ty, tx);
}

// ---------------- LDS-tiled conv 1->32 (c1), weights in LDS ----------------
__global__ __launch_bounds__(256, 4)
void k_conv1t(const float* __restrict__ in, const float* __restrict__ wr,
              const float* __restrict__ bias, const float* __restrict__ mo,
              float* __restrict__ out,
              int Zi, int Yi, int Xi, int Zo, int Yo, int Xo,
              int tilesZ, int tilesY, int tilesX) {
  __shared__ float sinf[NV];
  __shared__ float4 wsh[512];   // 64 taps x 8 co-quads
  {
    const float4* wr4 = (const float4*)wr;
    for (int idx = threadIdx.x; idx < 512; idx += 256) wsh[idx] = wr4[idx];
  }
  const int perIn = Zi * Yi * Xi;
  const int perOut = Zo * Yo * Xo;
  int bid = blockIdx.x;
  int txi = bid % tilesX; bid /= tilesX;
  int tyi = bid % tilesY; bid /= tilesY;
  int tzi = bid % tilesZ; int item = bid / tilesZ;
  const int z0 = tzi * TZ, y0 = tyi * TY, x0 = txi * TXT;
  const int tid = threadIdx.x;
  const int ox = tid & 15, oy = (tid >> 4) & 3, oz = tid >> 6;

  const float* inb = in + (size_t)item * perIn;
  for (int idx = tid; idx < NV; idx += 256) {
    int iz = idx / (IY * IX); int r = idx - iz * (IY * IX);
    int iy = r / IX; int ix = r - iy * IX;
    int gz = z0 + iz, gy = y0 + iy, gx = x0 + ix;
    float val = 0.f;
    if (gz < Zi && gy < Yi && gx < Xi)
      val = inb[(size_t)((gz * Yi + gy) * Xi + gx)];
    sinf[idx] = val;
  }
  __syncthreads();

  float4 acc[8];
#pragma unroll
  for (int j = 0; j < 8; ++j) acc[j] = make_float4(0.f, 0.f, 0.f, 0.f);

#pragma unroll 1
  for (int tap = 0; tap < 64; ++tap) {
    int kz = tap >> 4, ky = (tap >> 2) & 3, kx = tap & 3;
    int lv = ((oz + kz) * IY + (oy + ky)) * IX + (ox + kx);
    float av = sinf[lv];
#pragma unroll
    for (int j = 0; j < 8; ++j) {
      float4 wvv = wsh[tap * 8 + j];
      acc[j].x = fmaf(av, wvv.x, acc[j].x);
      acc[j].y = fmaf(av, wvv.y, acc[j].y);
      acc[j].z = fmaf(av, wvv.z, acc[j].z);
      acc[j].w = fmaf(av, wvv.w, acc[j].w);
    }
  }

  int gz = z0 + oz, gy = y0 + oy, gx = x0 + ox;
  if (gz < Zo && gy < Yo && gx < Xo) {
    int ov = item * perOut + (gz * Yo + gy) * Xo + gx;
    bool act = mo[ov] > 0.f;
    const float4* b4 = (const float4*)bias;
    float* op = out + (size_t)ov * 32;
#pragma unroll
    for (int j = 0; j < 8; ++j) {
      float4 r = acc[j]; float4 bj = b4[j];
      r.x = lrelu(act ? (r.x + bj.x) : 0.f);
      r.y = lrelu(act ? (r.y + bj.y) : 0.f);
      r.z = lrelu(act ? (r.z + bj.z) : 0.f);
      r.w = lrelu(act ? (r.w + bj.w) : 0.f);
      *(float4*)(op + j * 4) = r;
    }
  }
}

// ---------------- LDS-tiled conv 32->1 (c7), weights in LDS ----------------
// Output feeds p3 maxpool: NINF for inactive (sentinel trick).
__global__ __launch_bounds__(256, 2)
void k_conv7t(const float* __restrict__ in, const float* __restrict__ wr,
              const float* __restrict__ bias, const float* __restrict__ mo,
              float* __restrict__ out,
              int Zi, int Yi, int Xi, int Zo, int Yo, int Xo,
              int tilesZ, int tilesY, int tilesX) {
  __shared__ float4 sin4[4][NV];
  __shared__ float4 wsh[512];   // 64 taps x 8 ci-quads
  {
    const float4* wr4 = (const float4*)wr;
    for (int idx = threadIdx.x; idx < 512; idx += 256) wsh[idx] = wr4[idx];
  }
  const int perIn = Zi * Yi * Xi;
  const int perOut = Zo * Yo * Xo;
  int bid = blockIdx.x;
  int txi = bid % tilesX; bid /= tilesX;
  int tyi = bid % tilesY; bid /= tilesY;
  int tzi = bid % tilesZ; int item = bid / tilesZ;
  const int z0 = tzi * TZ, y0 = tyi * TY, x0 = txi * TXT;
  const int tid = threadIdx.x;
  const int ox = tid & 15, oy = (tid >> 4) & 3, oz = tid >> 6;

  const float* inb = in + (size_t)item * perIn * 32;
  float acc = 0.f;

#pragma unroll 1
  for (int h = 0; h < 2; ++h) {
    __syncthreads();
    for (int idx = tid; idx < NV * 4; idx += 256) {
      int q = idx / NV; int v = idx - q * NV;
      int iz = v / (IY * IX); int r = v - iz * (IY * IX);
      int iy = r / IX; int ix = r - iy * IX;
      int gz = z0 + iz, gy = y0 + iy, gx = x0 + ix;
      float4 val = make_float4(0.f, 0.f, 0.f, 0.f);
      if (gz < Zi && gy < Yi && gx < Xi)
        val = *(const float4*)(inb + (size_t)((gz * Yi + gy) * Xi + gx) * 32 + h * 16 + q * 4);
      sin4[q][v] = val;
    }
    __syncthreads();
#pragma unroll 1
    for (int tap = 0; tap < 64; ++tap) {
      int kz = tap >> 4, ky = (tap >> 2) & 3, kx = tap & 3;
      int lv = ((oz + kz) * IY + (oy + ky)) * IX + (ox + kx);
      float4 a0 = sin4[0][lv];
      float4 a1 = sin4[1][lv];
      float4 a2 = sin4[2][lv];
      float4 a3 = sin4[3][lv];
      float4 w0 = wsh[tap * 8 + h * 4 + 0];
      float4 w1 = wsh[tap * 8 + h * 4 + 1];
      float4 w2 = wsh[tap * 8 + h * 4 + 2];
      float4 w3 = wsh[tap * 8 + h * 4 + 3];
      acc += a0.x*w0.x + a0.y*w0.y + a0.z*w0.z + a0.w*w0.w
           + a1.x*w1.x + a1.y*w1.y + a1.z*w1.z + a1.w*w1.w
           + a2.x*w2.x + a2.y*w2.y + a2.z*w2.z + a2.w*w2.w
           + a3.x*w3.x + a3.y*w3.y + a3.z*w3.z + a3.w*w3.w;
    }
  }

  int gz = z0 + oz, gy = y0 + oy, gx = x0 + ox;
  if (gz < Zo && gy < Yo && gx < Xo) {
    int ov = item * perOut + (gz * Yo + gy) * Xo + gx;
    bool act = mo[ov] > 0.f;
    out[ov] = act ? lrelu(acc + bias[0]) : NINF;
  }
}

// ---------------- pool z-walk (C=32, float4/thread, rotating 5-window) ---------
__global__ void k_pool_zw(const float* __restrict__ in, float* __restrict__ out,
                          int Zi, int Yi, int Xi, int Zo, int nI) {
  int gid = blockIdx.x * blockDim.x + threadIdx.x;
  int nCh = (Zo + PCZ - 1) / PCZ;
  int perI = nCh * Yi * Xi * 8;
  if (gid >= nI * perI) return;
  int c4 = gid & 7; int t = gid >> 3;
  int x = t % Xi; t /= Xi;
  int y = t % Yi; t /= Yi;
  int ch = t % nCh; int item = t / nCh;
  int z0 = ch * PCZ;
  int zend = z0 + PCZ; if (zend > Zo) zend = Zo;

  const float* colp = in + ((size_t)((item * Zi) * Yi + y) * Xi + x) * 32 + c4 * 4;
  const size_t zs = (size_t)Yi * Xi * 32;
  float* ocolp = out + ((size_t)((item * Zo) * Yi + y) * Xi + x) * 32 + c4 * 4;

  float4 w0 = *(const float4*)(colp + (size_t)(z0 + 0) * zs);
  float4 w1 = *(const float4*)(colp + (size_t)(z0 + 1) * zs);
  float4 w2 = *(const float4*)(colp + (size_t)(z0 + 2) * zs);
  float4 w3 = *(const float4*)(colp + (size_t)(z0 + 3) * zs);
#pragma unroll 2
  for (int z = z0; z < zend; ++z) {
    float4 c = *(const float4*)(colp + (size_t)(z + 4) * zs);
    float4 m = max4(max4(w0, w1), max4(w2, max4(w3, c)));
    *(float4*)(ocolp + (size_t)z * zs) = m;
    w0 = w1; w1 = w2; w2 = w3; w3 = c;
  }
}

// ---------------- fused pool y+x (C=32, float4/thread, 4-wide x-run) ----------
__global__ void k_pool_yx(const float* __restrict__ in, const float* __restrict__ mp,
                          float* __restrict__ out,
                          int Z, int Yi, int Xi, int Yo, int Xo, int nI) {
  int gid = blockIdx.x * blockDim.x + threadIdx.x;
  int runsX = (Xo + 3) >> 2;
  int perR = Z * Yo * runsX;
  int tot = nI * perR * 8;
  if (gid >= tot) return;
  int c4 = gid & 7; int r = gid >> 3;
  int item = r / perR;
  int rr = r - item * perR;
  int xr = rr % runsX; int t = rr / runsX;
  int y = t % Yo; int z = t / Yo;
  int x0 = xr << 2;
  const float* ib = in + (size_t)item * Z * Yi * Xi * 32;

  float4 ym[8];
#pragma unroll
  for (int dx = 0; dx < 8; ++dx) ym[dx] = make_float4(NINF, NINF, NINF, NINF);
#pragma unroll
  for (int dy = 0; dy < 5; ++dy) {
    const float* rowb = ib + (size_t)((z * Yi + y + dy) * Xi) * 32;
#pragma unroll
    for (int dx = 0; dx < 8; ++dx) {
      int xx = x0 + dx;
      if (xx < Xi) {
        float4 v = *(const float4*)(rowb + (size_t)xx * 32 + c4 * 4);
        ym[dx] = max4(ym[dx], v);
      }
    }
  }
  int perOut = Z * Yo * Xo;
#pragma unroll
  for (int j = 0; j < 4; ++j) {
    int xx = x0 + j;
    if (xx < Xo) {
      float4 a = ym[j];
#pragma unroll
      for (int d = 1; d < 5; ++d) a = max4(a, ym[j + d]);
      int v = item * perOut + (z * Yo + y) * Xo + xx;
      bool act = mp[v] > 0.f;
      float4 rrv;
      rrv.x = act ? a.x : 0.f; rrv.y = act ? a.y : 0.f;
      rrv.z = act ? a.z : 0.f; rrv.w = act ? a.w : 0.f;
      *(float4*)(out + (size_t)v*32 + c4*4) = rrv;
    }
  }
}

// ---------------- final pool (C=1, direct 5^3), maskless via NINF sentinel ----
__global__ void k_pool3(const float* __restrict__ xin,
                        const float* __restrict__ mp, float* __restrict__ out, int nI) {
  int gid = blockIdx.x * blockDim.x + threadIdx.x;
  int perOut = 17 * 27 * 32;
  int tot = nI * perOut;
  if (gid >= tot) return;
  int item = gid / perOut;
  int r = gid - item * perOut;
  int x = r & 31; int t = r >> 5;
  int y = t % 27; int z = t / 27;
  const float* xb = xin + (size_t)item * 23436;
  float acc = NINF;
  for (int dz = 0; dz < 5; dz++)
    for (int dy = 0; dy < 5; dy++) {
      const float* rowx = xb + (size_t)(((z + dz)*31 + y + dy)*36 + x);
      for (int dx = 0; dx < 5; dx++)
        acc = fmaxf(acc, rowx[dx]);
    }
  out[gid] = (mp[gid] > 0.f) ? acc : 0.f;
}

// ---------------- FC split-K partial + finalize ----------------
__global__ __launch_bounds__(256, 4)
void k_fc_part(const float* __restrict__ X, const float* __restrict__ Wm,
               float* __restrict__ part, int K, int Ncol, int Kc) {
  __shared__ float sm[16][16][8];
  int ks = blockIdx.y;
  int k0 = ks * Kc;
  int k1 = k0 + Kc; if (k1 > K) k1 = K;
  int cl = threadIdx.x & 15;
  int kt = threadIdx.x >> 4;
  int col = blockIdx.x * 16 + cl;
  float a0=0.f,a1=0.f,a2=0.f,a3=0.f,a4=0.f,a5=0.f,a6=0.f,a7=0.f;
  if (col < Ncol) {
    for (int k = k0 + kt; k < k1; k += 16) {
      float w = Wm[(size_t)k * Ncol + col];
      a0 += X[0 * K + k] * w; a1 += X[1 * K + k] * w;
      a2 += X[2 * K + k] * w; a3 += X[3 * K + k] * w;
      a4 += X[4 * K + k] * w; a5 += X[5 * K + k] * w;
      a6 += X[6 * K + k] * w; a7 += X[7 * K + k] * w;
    }
  }
  sm[kt][cl][0]=a0; sm[kt][cl][1]=a1; sm[kt][cl][2]=a2; sm[kt][cl][3]=a3;
  sm[kt][cl][4]=a4; sm[kt][cl][5]=a5; sm[kt][cl][6]=a6; sm[kt][cl][7]=a7;
  __syncthreads();
  if (threadIdx.x < 128) {
    int c = threadIdx.x & 15;
    int b = threadIdx.x >> 4;
    float s = 0.f;
#pragma unroll
    for (int k = 0; k < 16; k++) s += sm[k][c][b];
    int cc = blockIdx.x * 16 + c;
    if (cc < Ncol) part[((size_t)ks * 8 + b) * Ncol + cc] = s;
  }
}

__global__ void k_fc_fin(const float* __restrict__ part, int ns,
                         const float* __restrict__ bias, float* __restrict__ out, int Ncol) {
  int i = blockIdx.x * blockDim.x + threadIdx.x;
  if (i >= 8 * Ncol) return;
  int b = i / Ncol;
  int c = i - b * Ncol;
  float s = 0.f;
  for (int ks = 0; ks < ns; ks++) s += part[((size_t)ks * 8 + b) * Ncol + c];
  out[i] = lrelu(s + bias[c]);
}

// last FC (K=1000 -> 1), small
__global__ __launch_bounds__(256, 4)
void k_fc(const float* __restrict__ X, const float* __restrict__ Wm,
          const float* __restrict__ bias, float* __restrict__ out,
          int K, int Ncol) {
  __shared__ float sm[16][16][8];
  int cl = threadIdx.x & 15;
  int kt = threadIdx.x >> 4;
  int col = blockIdx.x * 16 + cl;
  float a0=0.f,a1=0.f,a2=0.f,a3=0.f,a4=0.f,a5=0.f,a6=0.f,a7=0.f;
  if (col < Ncol) {
    for (int k = kt; k < K; k += 16) {
      float w = Wm[(size_t)k * Ncol + col];
      a0 += X[0 * K + k] * w; a1 += X[1 * K + k] * w;
      a2 += X[2 * K + k] * w; a3 += X[3 * K + k] * w;
      a4 += X[4 * K + k] * w; a5 += X[5 * K + k] * w;
      a6 += X[6 * K + k] * w; a7 += X[7 * K + k] * w;
    }
  }
  sm[kt][cl][0]=a0; sm[kt][cl][1]=a1; sm[kt][cl][2]=a2; sm[kt][cl][3]=a3;
  sm[kt][cl][4]=a4; sm[kt][cl][5]=a5; sm[kt][cl][6]=a6; sm[kt][cl][7]=a7;
  __syncthreads();
  if (threadIdx.x < 128) {
    int c = threadIdx.x & 15;
    int b = threadIdx.x >> 4;
    float s = 0.f;
#pragma unroll
    for (int k = 0; k < 16; k++) s += sm[k][c][b];
    int cc = blockIdx.x * 16 + c;
    if (cc < Ncol) out[b * Ncol + cc] = lrelu(s + bias[cc]);
  }
}

// ---------------- host ----------------
static inline int G256(long long n) { return (int)((n + 255) / 256); }

extern "C" void kernel_launch(void* const* d_in, const int* in_sizes, int n_in,
                              void* d_out, int out_size, void* d_ws, size_t ws_size,
                              hipStream_t stream) {
  const float* feat  = (const float*)d_in[0];
  const int*   coors = (const int*)d_in[1];
  const float* w1 = (const float*)d_in[3];  const float* b1 = (const float*)d_in[4];
  const float* w2 = (const float*)d_in[5];  const float* b2 = (const float*)d_in[6];
  const float* w3 = (const float*)d_in[7];  const float* b3 = (const float*)d_in[8];
  const float* w4 = (const float*)d_in[9];  const float* b4 = (const float*)d_in[10];
  const float* w5 = (const float*)d_in[11]; const float* b5 = (const float*)d_in[12];
  const float* w6 = (const float*)d_in[13]; const float* b6 = (const float*)d_in[14];
  const float* w7 = (const float*)d_in[15]; const float* b7 = (const float*)d_in[16];
  const float* W8 = (const float*)d_in[17]; const float* b8 = (const float*)d_in[18];
  const float* W9 = (const float*)d_in[19]; const float* b9 = (const float*)d_in[20];
  const float* W10= (const float*)d_in[21]; const float* b10= (const float*)d_in[22];
  float* out = (float*)d_out;

  char* ws = (char*)d_ws;
  size_t off = 0;
  auto alloc = [&](size_t nfloats) -> float* {
    float* p = (float*)(ws + off);
    off += ((nfloats * 4 + 1023) / 1024) * 1024;
    return p;
  };

  // ---- fixed allocations ----
  float* x0  = alloc(1560000);
  float* m0  = alloc(1560000);
  float* m1  = alloc(8 * 166098);
  float* m2  = alloc(8 * 140184);
  float* mp1 = alloc(8 * 110000);
  float* m3  = alloc(8 * 90428);
  float* m4  = alloc(8 * 73304);
  float* mp2 = alloc(8 * 54000);
  float* m5  = alloc(8 * 41958);
  float* m6  = alloc(8 * 31824);
  float* m7  = alloc(8 * 23436);
  float* mp3 = alloc(8 * 14688);
  float* p3  = alloc(8 * 14688);
  float* wr1 = alloc(2048);
  float* wr7 = alloc(2048);
  unsigned short* tb2 = (unsigned short*)alloc(131072);   // 5 contiguous 512 KB tables
  unsigned short* tb3 = (unsigned short*)alloc(131072);
  unsigned short* tb4 = (unsigned short*)alloc(131072);
  unsigned short* tb5 = (unsigned short*)alloc(131072);
  unsigned short* tb6 = (unsigned short*)alloc(131072);
  float* part= alloc(64000);
  float* h8  = alloc(8000);
  float* h9  = alloc(8000);
  size_t fixedOff = off;

  // ---- pick group size G from remaining workspace ----
  const size_t perItemAB = ((size_t)5315136*4 + 1023)/1024*1024
                         + ((size_t)4485888*4 + 1023)/1024*1024
                         + ((size_t)23436*4 + 1023)/1024*1024;
  int G = 0;
  for (int g : {8, 4, 2, 1})
    if (fixedOff + (size_t)g * perItemAB <= ws_size) { G = g; break; }
  if (G == 0) return;

  float* A  = alloc((size_t)G * 5315136);
  float* Bb = alloc((size_t)G * 4485888);
  float* x7 = alloc((size_t)G * 23436);
  unsigned* claim = (unsigned*)A;   // claim aliases A (dead before first conv use)

  // ---- init ----
  hipMemsetAsync(claim, 0, 1560000 * 4, stream);
  // x0 and m0 are adjacent 1KB-padded allocations (6240256 B each);
  // zero both in one call without touching m1.
  hipMemsetAsync(x0, 0, 6240256 + 6240000, stream);

  k_repack_all<<<dim3(128, 7), 256, 0, stream>>>(w2, w3, w4, w5, w6, w1, w7,
                                                 tb2, wr1, wr7);

  const int N = 80000;
  k_claim  <<<G256(N), 256, 0, stream>>>(coors, claim, N);
  k_scatter<<<G256(N), 256, 0, stream>>>(coors, feat, claim, x0, m0, N);

  // ---- two-stage fused mask dilations (5 launches for the 10-stage chain) ----
  auto dil2 = [&](const float* src, float* o1, float* o2,
                  int Z0,int Y0,int X0, int Z1,int Y1,int X1, int Z2,int Y2,int X2,
                  int K1, int K2) {
    int tz = (Z2 + 3) / 4, ty = (Y2 + 7) / 8, tx = (X2 + 31) / 32;
    int g = 8 * tz * ty * tx;
    if (K1 == 4 && K2 == 4)
      kd_fused2<4,4><<<g, 256, 0, stream>>>(src, o1, o2, Z0,Y0,X0, Z1,Y1,X1, Z2,Y2,X2, tz,ty,tx);
    else if (K1 == 5)
      kd_fused2<5,4><<<g, 256, 0, stream>>>(src, o1, o2, Z0,Y0,X0, Z1,Y1,X1, Z2,Y2,X2, tz,ty,tx);
    else
      kd_fused2<4,5><<<g, 256, 0, stream>>>(src, o1, o2, Z0,Y0,X0, Z1,Y1,X1, Z2,Y2,X2, tz,ty,tx);
  };
  dil2(m0,  m1, m2,  50,60,65, 47,57,62, 44,54,59, 4,4);
  dil2(m2,  mp1, m3, 44,54,59, 40,50,55, 37,47,52, 5,4);
  dil2(m3,  m4, mp2, 37,47,52, 34,44,49, 30,40,45, 4,5);
  dil2(mp2, m5, m6,  30,40,45, 27,37,42, 24,34,39, 4,4);
  dil2(m6,  m7, mp3, 24,34,39, 21,31,36, 17,27,32, 4,5);

  for (int g0 = 0; g0 < 8; g0 += G) {
    const float* x0g  = x0  + (size_t)g0 * 195000;
    const float* m1g  = m1  + (size_t)g0 * 166098;
    const float* m2g  = m2  + (size_t)g0 * 140184;
    const float* mp1g = mp1 + (size_t)g0 * 110000;
    const float* m3g  = m3  + (size_t)g0 * 90428;
    const float* m4g  = m4  + (size_t)g0 * 73304;
    const float* mp2g = mp2 + (size_t)g0 * 54000;
    const float* m5g  = m5  + (size_t)g0 * 41958;
    const float* m6g  = m6  + (size_t)g0 * 31824;
    const float* m7g  = m7  + (size_t)g0 * 23436;
    const float* mp3g = mp3 + (size_t)g0 * 14688;

    // c1: 50,60,65 -> 47,57,62
    {
      int tz = (47 + TZ - 1) / TZ, ty = (57 + TY - 1) / TY, tx = (62 + TXT - 1) / TXT;
      k_conv1t<<<G * tz * ty * tx, 256, 0, stream>>>(
          x0g, wr1, b1, m1g, A, 50,60,65, 47,57,62, tz, ty, tx);
    }
    // c2 -> 44,54,59   tile (4,4,16); POOLOUT (feeds p1)
    launch_conv32<4,4,16,7,7,19,true>(stream, A, tb2, b2, m2g, Bb, 47,57,62, 44,54,59, G);
    // p1 -> 40,50,55  (z-walk maskless; fused yx with mp gate)
    {
      int nCh = (40 + PCZ - 1) / PCZ;
      k_pool_zw<<<G256((long long)G * nCh * 54 * 59 * 8), 256, 0, stream>>>(Bb, A, 44,54,59, 40, G);
    }
    k_pool_yx<<<G256((long long)G*40*50*14*8), 256, 0, stream>>>(A, mp1g, Bb, 40,54,59, 50,55, G);
    // c3 -> 37,47,52   tile (8,8,4)
    launch_conv32<8,8,4,11,11,7,false>(stream, Bb, tb3, b3, m3g, A, 40,50,55, 37,47,52, G);
    // c4 -> 34,44,49   tile (4,16,4); POOLOUT (feeds p2)
    launch_conv32<4,16,4,7,19,7,true>(stream, A, tb4, b4, m4g, Bb, 37,47,52, 34,44,49, G);
    // p2 -> 30,40,45
    {
      int nCh = (30 + PCZ - 1) / PCZ;
      k_pool_zw<<<G256((long long)G * nCh * 44 * 49 * 8), 256, 0, stream>>>(Bb, A, 34,44,49, 30, G);
    }
    k_pool_yx<<<G256((long long)G*30*40*12*8), 256, 0, stream>>>(A, mp2g, Bb, 30,44,49, 40,45, G);
    // c5 -> 27,37,42   tile (4,4,16)
    launch_conv32<4,4,16,7,7,19,false>(stream, Bb, tb5, b5, m5g, A, 30,40,45, 27,37,42, G);
    // c6 -> 24,34,39   tile (8,4,8)
    launch_conv32<8,4,8,11,7,11,false>(stream, A, tb6, b6, m6g, Bb, 27,37,42, 24,34,39, G);
    // c7 (32->1) -> 21,31,36  (NINF sentinel out, feeds p3)
    {
      int tz = (21 + TZ - 1) / TZ, ty = (31 + TY - 1) / TY, tx = (36 + TXT - 1) / TXT;
      k_conv7t<<<G * tz * ty * tx, 256, 0, stream>>>(
          Bb, wr7, b7, m7g, x7, 24,34,39, 21,31,36, tz, ty, tx);
    }
    // p3 -> 17,27,32  (maskless 5^3 + mp gate)
    k_pool3<<<G256((long long)G*14688), 256, 0, stream>>>(
        x7, mp3g, p3 + (size_t)g0 * 14688, G);
  }

  // ---- FC head ----
  k_fc_part<<<dim3(63, 8), 256, 0, stream>>>(p3, W8, part, 14688, 1000, 1836);
  k_fc_fin <<<G256(8000), 256, 0, stream>>>(part, 8, b8, h8, 1000);
  k_fc_part<<<dim3(63, 4), 256, 0, stream>>>(h8, W9, part, 1000, 1000, 250);
  k_fc_fin <<<G256(8000), 256, 0, stream>>>(part, 4, b9, h9, 1000);
  k_fc<<<1, 256, 0, stream>>>(h9, W10, b10, out, 1000, 1);
}

// Round 12
// 2967.466 us; speedup vs baseline: 1.0359x; 1.0359x over previous
//
#include <hip/hip_runtime.h>
#include <cstddef>

// Sparse 3D CNN. R19: revert R18's kd_fused2 (2.6x redundant stage-1 halo
// recompute at 2 blk/CU => +83us regression; single-stage kd_fused restored,
// c1 back to bounds(256,2)). Kept: repack_all single launch, merged memset.
// NEW: k_pool_yw + k_pool_xw replace fused k_pool_yx. The fused yx read 40
// float4 per 4 outputs (10x amplification: p1 163MB/item, p2 82MB/item);
// walk kernels (proven pool_zw register-window pattern) read ~1.05-1.4x.
// Traffic p1 177->60MB/item, p2 89->30MB/item. Buffers re-ping-ponged:
// zw B->A, yw A->B, xw B->A(gated); c3 A->Bb; c4 Bb->A; p2 zw A->B,
// yw B->A, xw A->B; c5 Bb->A; c6 A->Bb; c7 Bb->x7.
// conv32m CLOSED at ~377us c2 (7 falsified attempts). R17: pool_zw z-walk.
// R15: LDS kd_fused dilations. R14: NINF sentinel + maskless pools.
// R13: conv32m tiles c3(8,8,4) c4(4,16,4) c6(8,4,8).
// Chain: 50,60,65 -> c1 47,57,62 -> c2 44,54,59 -> p1 40,50,55 -> c3 37,47,52
// -> c4 34,44,49 -> p2 30,40,45 -> c5 27,37,42 -> c6 24,34,39 -> c7 21,31,36
// -> p3 17,27,32 ; flatten 14688 -> FC 1000 -> 1000 -> 1

#define NEGSLOPE 0.01f
#define NINF (-3.0e38f)

// c1/c7 tile geometry: 4x4x16 out, 7x7x19 halo
#define TZ 4
#define TY 4
#define TXT 16
#define IZ 7
#define IY 7
#define IX 19
#define NV (IZ*IY*IX)    // 931 voxels

#define PCZ 10           // pool walk chunk (outputs per thread)

typedef __attribute__((ext_vector_type(8)))  short    short8;    // 8 bf16
typedef __attribute__((ext_vector_type(4)))  unsigned uint4v;
typedef __attribute__((ext_vector_type(16))) float    floatx16;  // 32x32 acc

constexpr int ilog2c(int v) { return v == 1 ? 0 : 1 + ilog2c(v / 2); }

__device__ __forceinline__ float lrelu(float v) { return v >= 0.f ? v : NEGSLOPE * v; }

__device__ __forceinline__ unsigned short f2bf(float f) {
  unsigned b = __float_as_uint(f);
  return (unsigned short)((b + 0x7fffu + ((b >> 16) & 1u)) >> 16);   // RNE
}
__device__ __forceinline__ float bf2f(unsigned short h) {
  return __uint_as_float(((unsigned)h) << 16);
}
__device__ __forceinline__ unsigned splitpair(float a, float b, unsigned& lo) {
  unsigned short ha = f2bf(a), hb = f2bf(b);
  unsigned short la = f2bf(a - bf2f(ha)), lb = f2bf(b - bf2f(hb));
  lo = (unsigned)la | ((unsigned)lb << 16);
  return (unsigned)ha | ((unsigned)hb << 16);
}

__device__ __forceinline__ float4 max4(float4 a, float4 b) {
  float4 r;
  r.x = fmaxf(a.x, b.x); r.y = fmaxf(a.y, b.y);
  r.z = fmaxf(a.z, b.z); r.w = fmaxf(a.w, b.w);
  return r;
}

// load A-frag (8 bf16) from LDS at 40B voxel stride; oct 0 = hi, oct 1 = lo
__device__ __forceinline__ short8 ld_frag(const uint2* s2, int v, int oct) {
  uint2 u0 = s2[v * 5 + oct * 2];
  uint2 u1 = s2[v * 5 + oct * 2 + 1];
  uint4v t; t.x = u0.x; t.y = u0.y; t.z = u1.x; t.w = u1.y;
  return __builtin_bit_cast(short8, t);
}

// ---------------- scatter (last-write-wins), full batch ----------------
__global__ void k_claim(const int* __restrict__ coors, unsigned* __restrict__ claim, int N) {
  int i = blockIdx.x * blockDim.x + threadIdx.x;
  if (i >= N) return;
  int b = coors[4*i], z = coors[4*i+1], y = coors[4*i+2], x = coors[4*i+3];
  int v = ((b*50 + z)*60 + y)*65 + x;
  atomicMax(&claim[v], (unsigned)(i + 1));
}

__global__ void k_scatter(const int* __restrict__ coors, const float* __restrict__ feat,
                          const unsigned* __restrict__ claim,
                          float* __restrict__ x0, float* __restrict__ m0, int N) {
  int i = blockIdx.x * blockDim.x + threadIdx.x;
  if (i >= N) return;
  int b = coors[4*i], z = coors[4*i+1], y = coors[4*i+2], x = coors[4*i+3];
  int v = ((b*50 + z)*60 + y)*65 + x;
  m0[v] = 1.f;
  if (claim[v] == (unsigned)(i + 1)) x0[v] = feat[i];
}

// ---------------- unified weight repack: 5 MFMA tables + wr1 + wr7 ----------------
__global__ void k_repack_all(const float* __restrict__ wA, const float* __restrict__ wB,
                             const float* __restrict__ wC, const float* __restrict__ wD,
                             const float* __restrict__ wE,
                             const float* __restrict__ w1, const float* __restrict__ w7,
                             unsigned short* __restrict__ tbl0,
                             float* __restrict__ wr1, float* __restrict__ wr7) {
  int layer = blockIdx.y;
  int i = blockIdx.x * blockDim.x + threadIdx.x;
  if (layer >= 5) {
    if (i < 2048) {
      int k = i & 63;
      if (layer == 5) { int co = i >> 6; wr1[k * 32 + co] = w1[i]; }
      else           { int ci = (i >> 6) & 31; wr7[k * 32 + ci] = w7[i]; }
    }
    return;
  }
  const float* w = layer == 0 ? wA : layer == 1 ? wB : layer == 2 ? wC
                 : layer == 3 ? wD : wE;
  unsigned short* tbl = tbl0 + (size_t)layer * 262144;   // 512 KB / 2B
  if (i >= 64*4*2*64) return;
  int lane = i & 63; int t = i >> 6;
  int pack = t & 1; t >>= 1;
  int pass = t & 3; int tap = t >> 2;
  int co = lane & 31; int oct = lane >> 5;
#pragma unroll
  for (int j = 0; j < 8; ++j) {
    int k = oct * 8 + j;
    int ci = pass * 8 + (k & 7);
    int part = ((k >> 3) ^ pack) & 1;
    float wv = w[((co * 32 + ci) << 6) + tap];
    unsigned short wh = f2bf(wv);
    unsigned short r = part ? f2bf(wv - bf2f(wh)) : wh;
    tbl[(size_t)i * 8 + j] = r;
  }
}

// ---------------- fused separable mask dilation (z,y,x in LDS), 1 stage -------
template<int K>
__global__ __launch_bounds__(256, 4)
void kd_fused(const float* __restrict__ in, float* __restrict__ out,
              int Zi, int Yi, int Xi, int Zo, int Yo, int Xo,
              int tilesZ, int tilesY, int tilesX) {
  constexpr int TDZ = 4, TDY = 8, TDX = 32;
  constexpr int HZ = TDZ + K - 1, HY = TDY + K - 1, HX = TDX + K - 1;
  __shared__ float sA[HZ * HY * HX];
  __shared__ float sB[TDZ * HY * HX];
  __shared__ float sC[TDZ * TDY * HX];
  int bid = blockIdx.x;
  int txi = bid % tilesX; bid /= tilesX;
  int tyi = bid % tilesY; bid /= tilesY;
  int tzi = bid % tilesZ; int item = bid / tilesZ;
  const int z0 = tzi * TDZ, y0 = tyi * TDY, x0 = txi * TDX;
  const int tid = threadIdx.x;
  const float* ib = in + (size_t)item * Zi * Yi * Xi;

  for (int idx = tid; idx < HZ * HY * HX; idx += 256) {
    int iz = idx / (HY * HX); int r = idx - iz * (HY * HX);
    int iy = r / HX; int ix = r - iy * HX;
    int gz = z0 + iz, gy = y0 + iy, gx = x0 + ix;
    float v = 0.f;
    if (gz < Zi && gy < Yi && gx < Xi) v = ib[((size_t)gz * Yi + gy) * Xi + gx];
    sA[idx] = v;
  }
  __syncthreads();
  for (int idx = tid; idx < TDZ * HY * HX; idx += 256) {
    int z = idx / (HY * HX); int r = idx - z * (HY * HX);
    float m = 0.f;
#pragma unroll
    for (int d = 0; d < K; ++d) m = fmaxf(m, sA[(z + d) * (HY * HX) + r]);
    sB[idx] = m;
  }
  __syncthreads();
  for (int idx = tid; idx < TDZ * TDY * HX; idx += 256) {
    int z = idx / (TDY * HX); int r = idx - z * (TDY * HX);
    int y = r / HX; int x = r - y * HX;
    float m = 0.f;
#pragma unroll
    for (int d = 0; d < K; ++d) m = fmaxf(m, sB[z * (HY * HX) + (y + d) * HX + x]);
    sC[idx] = m;
  }
  __syncthreads();
  const int perOut = Zo * Yo * Xo;
  for (int idx = tid; idx < TDZ * TDY * TDX; idx += 256) {
    int z = idx / (TDY * TDX); int r = idx - z * (TDY * TDX);
    int y = r / TDX; int x = r - y * TDX;
    int gz = z0 + z, gy = y0 + y, gx = x0 + x;
    if (gz < Zo && gy < Yo && gx < Xo) {
      float m = 0.f;
#pragma unroll
      for (int d = 0; d < K; ++d) m = fmaxf(m, sC[z * (TDY * HX) + y * HX + x + d]);
      out[(size_t)item * perOut + ((size_t)gz * Yo + gy) * Xo + gx] = m;
    }
  }
}

// ---------------- MFMA conv 32->32 (templated tile shape, R15 body) ----------------
template<int TZL, int TYL, int TXL, int IZL, int IYL, int IXL, bool POOLOUT>
__global__ __launch_bounds__(256, 4)
void k_conv32m(const float* __restrict__ in, const unsigned short* __restrict__ tbl,
               const float* __restrict__ bias, const float* __restrict__ mo,
               float* __restrict__ out,
               int Zi, int Yi, int Xi, int Zo, int Yo, int Xo,
               int tilesZ, int tilesY, int tilesX) {
  constexpr int NVL = IZL * IYL * IXL;
  constexpr int LXs = ilog2c(TXL);
  constexpr int LYs = ilog2c(TYL);
  __shared__ unsigned sU[NVL * 10];
  const int perIn = Zi * Yi * Xi;
  const int perOut = Zo * Yo * Xo;
  int bid = blockIdx.x;
  int txi = bid % tilesX; bid /= tilesX;
  int tyi = bid % tilesY; bid /= tilesY;
  int tzi = bid % tilesZ; int item = bid / tilesZ;
  const int z0 = tzi * TZL, y0 = tyi * TYL, x0 = txi * TXL;
  const int tid = threadIdx.x;
  const int lane = tid & 63;
  const int col = lane & 31;     // co (B n-index) and A-row m
  const int oct = lane >> 5;
  const int wv  = tid >> 6;      // wave 0..3

  int lvBase0, lvBase1;
  {
    int vt0 = (2*wv + 0)*32 + col;
    int vt1 = (2*wv + 1)*32 + col;
    lvBase0 = ((vt0 >> (LXs+LYs))*IYL + ((vt0 >> LXs) & (TYL-1)))*IXL + (vt0 & (TXL-1));
    lvBase1 = ((vt1 >> (LXs+LYs))*IYL + ((vt1 >> LXs) & (TYL-1)))*IXL + (vt1 & (TXL-1));
  }

  floatx16 acc0, acc1;
#pragma unroll
  for (int r = 0; r < 16; ++r) { acc0[r] = 0.f; acc1[r] = 0.f; }

  const float* inb = in + (size_t)item * perIn * 32;
  const char* tb = (const char*)tbl + lane * 16;
  uint2* s2 = (uint2*)sU;

#pragma unroll 1
  for (int p = 0; p < 4; ++p) {
    __syncthreads();
    for (int idx = tid; idx < NVL; idx += 256) {
      int iz = idx / (IYL * IXL); int r = idx - iz * (IYL * IXL);
      int iy = r / IXL; int ix = r - iy * IXL;
      int gz = z0 + iz, gy = y0 + iy, gx = x0 + ix;
      float4 f0 = make_float4(0.f,0.f,0.f,0.f), f1 = make_float4(0.f,0.f,0.f,0.f);
      if (gz < Zi && gy < Yi && gx < Xi) {
        const float* vp = inb + (size_t)((gz * Yi + gy) * Xi + gx) * 32 + p * 8;
        f0 = *(const float4*)vp;
        f1 = *(const float4*)(vp + 4);
      }
      unsigned l0, l1, l2, l3;
      unsigned h0 = splitpair(f0.x, f0.y, l0);
      unsigned h1 = splitpair(f0.z, f0.w, l1);
      unsigned h2 = splitpair(f1.x, f1.y, l2);
      unsigned h3 = splitpair(f1.z, f1.w, l3);
      s2[idx * 5 + 0] = make_uint2(h0, h1);
      s2[idx * 5 + 1] = make_uint2(h2, h3);
      s2[idx * 5 + 2] = make_uint2(l0, l1);
      s2[idx * 5 + 3] = make_uint2(l2, l3);
    }
    __syncthreads();

    const char* tp = tb + (size_t)p * 2048;
#pragma unroll 2
    for (int tap = 0; tap < 64; ++tap) {
      int kz = tap >> 4, ky = (tap >> 2) & 3, kx = tap & 3;
      int sOff = (kz * IYL + ky) * IXL + kx;
      short8 b0 = *(const short8*)(tp + (size_t)tap * 8192);
      short8 b1 = *(const short8*)(tp + (size_t)tap * 8192 + 1024);
      short8 a0 = ld_frag(s2, lvBase0 + sOff, oct);
      short8 a1 = ld_frag(s2, lvBase1 + sOff, oct);
      acc0 = __builtin_amdgcn_mfma_f32_32x32x16_bf16(a0, b0, acc0, 0, 0, 0);
      acc0 = __builtin_amdgcn_mfma_f32_32x32x16_bf16(a0, b1, acc0, 0, 0, 0);
      acc1 = __builtin_amdgcn_mfma_f32_32x32x16_bf16(a1, b0, acc1, 0, 0, 0);
      acc1 = __builtin_amdgcn_mfma_f32_32x32x16_bf16(a1, b1, acc1, 0, 0, 0);
    }
  }

  // epilogue: C/D layout col=lane&31 (co), row m=(reg&3)+8*(reg>>2)+4*oct
  const float bco = bias[col];
#pragma unroll
  for (int gg = 0; gg < 2; ++gg) {
    int vtb = (2*wv + gg) * 32;
#pragma unroll
    for (int rg = 0; rg < 16; ++rg) {
      int row = (rg & 3) + 8 * (rg >> 2) + 4 * oct;
      int vt = vtb + row;
      int oz = vt >> (LXs+LYs), oy = (vt >> LXs) & (TYL-1), ox = vt & (TXL-1);
      int gz = z0 + oz, gy = y0 + oy, gx = x0 + ox;
      if (gz < Zo && gy < Yo && gx < Xo) {
        int ov = item * perOut + (gz * Yo + gy) * Xo + gx;
        float val = (gg == 0) ? acc0[rg] : acc1[rg];
        bool act = mo[ov] > 0.f;
        float vv = act ? lrelu(val + bco) : (POOLOUT ? NINF : 0.f);
        out[(size_t)ov * 32 + col] = vv;
      }
    }
  }
}

// host-side launcher for a given tile shape
template<int TZL, int TYL, int TXL, int IZL, int IYL, int IXL, bool POOLOUT>
static void launch_conv32(hipStream_t stream,
                          const float* in, const unsigned short* tbl, const float* bias,
                          const float* mo, float* o,
                          int Zi, int Yi, int Xi, int Zo, int Yo, int Xo, int nI) {
  int tz = (Zo + TZL - 1) / TZL, ty = (Yo + TYL - 1) / TYL, tx = (Xo + TXL - 1) / TXL;
  k_conv32m<TZL,TYL,TXL,IZL,IYL,IXL,POOLOUT><<<nI * tz * ty * tx, 256, 0, stream>>>(
      in, tbl, bias, mo, o, Zi, Yi, Xi, Zo, Yo, Xo, tz, ty, tx);
}

// ---------------- LDS-tiled conv 1->32 (c1), weights in LDS ----------------
__global__ __launch_bounds__(256, 2)
void k_conv1t(const float* __restrict__ in, const float* __restrict__ wr,
              const float* __restrict__ bias, const float* __restrict__ mo,
              float* __restrict__ out,
              int Zi, int Yi, int Xi, int Zo, int Yo, int Xo,
              int tilesZ, int tilesY, int tilesX) {
  __shared__ float sinf[NV];
  __shared__ float4 wsh[512];   // 64 taps x 8 co-quads
  {
    const float4* wr4 = (const float4*)wr;
    for (int idx = threadIdx.x; idx < 512; idx += 256) wsh[idx] = wr4[idx];
  }
  const int perIn = Zi * Yi * Xi;
  const int perOut = Zo * Yo * Xo;
  int bid = blockIdx.x;
  int txi = bid % tilesX; bid /= tilesX;
  int tyi = bid % tilesY; bid /= tilesY;
  int tzi = bid % tilesZ; int item = bid / tilesZ;
  const int z0 = tzi * TZ, y0 = tyi * TY, x0 = txi * TXT;
  const int tid = threadIdx.x;
  const int ox = tid & 15, oy = (tid >> 4) & 3, oz = tid >> 6;

  const float* inb = in + (size_t)item * perIn;
  for (int idx = tid; idx < NV; idx += 256) {
    int iz = idx / (IY * IX); int r = idx - iz * (IY * IX);
    int iy = r / IX; int ix = r - iy * IX;
    int gz = z0 + iz, gy = y0 + iy, gx = x0 + ix;
    float val = 0.f;
    if (gz < Zi && gy < Yi && gx < Xi)
      val = inb[(size_t)((gz * Yi + gy) * Xi + gx)];
    sinf[idx] = val;
  }
  __syncthreads();

  float4 acc[8];
#pragma unroll
  for (int j = 0; j < 8; ++j) acc[j] = make_float4(0.f, 0.f, 0.f, 0.f);

#pragma unroll 1
  for (int tap = 0; tap < 64; ++tap) {
    int kz = tap >> 4, ky = (tap >> 2) & 3, kx = tap & 3;
    int lv = ((oz + kz) * IY + (oy + ky)) * IX + (ox + kx);
    float av = sinf[lv];
#pragma unroll
    for (int j = 0; j < 8; ++j) {
      float4 wvv = wsh[tap * 8 + j];
      acc[j].x = fmaf(av, wvv.x, acc[j].x);
      acc[j].y = fmaf(av, wvv.y, acc[j].y);
      acc[j].z = fmaf(av, wvv.z, acc[j].z);
      acc[j].w = fmaf(av, wvv.w, acc[j].w);
    }
  }

  int gz = z0 + oz, gy = y0 + oy, gx = x0 + ox;
  if (gz < Zo && gy < Yo && gx < Xo) {
    int ov = item * perOut + (gz * Yo + gy) * Xo + gx;
    bool act = mo[ov] > 0.f;
    const float4* b4 = (const float4*)bias;
    float* op = out + (size_t)ov * 32;
#pragma unroll
    for (int j = 0; j < 8; ++j) {
      float4 r = acc[j]; float4 bj = b4[j];
      r.x = lrelu(act ? (r.x + bj.x) : 0.f);
      r.y = lrelu(act ? (r.y + bj.y) : 0.f);
      r.z = lrelu(act ? (r.z + bj.z) : 0.f);
      r.w = lrelu(act ? (r.w + bj.w) : 0.f);
      *(float4*)(op + j * 4) = r;
    }
  }
}

// ---------------- LDS-tiled conv 32->1 (c7), weights in LDS ----------------
// Output feeds p3 maxpool: NINF for inactive (sentinel trick).
__global__ __launch_bounds__(256, 2)
void k_conv7t(const float* __restrict__ in, const float* __restrict__ wr,
              const float* __restrict__ bias, const float* __restrict__ mo,
              float* __restrict__ out,
              int Zi, int Yi, int Xi, int Zo, int Yo, int Xo,
              int tilesZ, int tilesY, int tilesX) {
  __shared__ float4 sin4[4][NV];
  __shared__ float4 wsh[512];   // 64 taps x 8 ci-quads
  {
    const float4* wr4 = (const float4*)wr;
    for (int idx = threadIdx.x; idx < 512; idx += 256) wsh[idx] = wr4[idx];
  }
  const int perIn = Zi * Yi * Xi;
  const int perOut = Zo * Yo * Xo;
  int bid = blockIdx.x;
  int txi = bid % tilesX; bid /= tilesX;
  int tyi = bid % tilesY; bid /= tilesY;
  int tzi = bid % tilesZ; int item = bid / tilesZ;
  const int z0 = tzi * TZ, y0 = tyi * TY, x0 = txi * TXT;
  const int tid = threadIdx.x;
  const int ox = tid & 15, oy = (tid >> 4) & 3, oz = tid >> 6;

  const float* inb = in + (size_t)item * perIn * 32;
  float acc = 0.f;

#pragma unroll 1
  for (int h = 0; h < 2; ++h) {
    __syncthreads();
    for (int idx = tid; idx < NV * 4; idx += 256) {
      int q = idx / NV; int v = idx - q * NV;
      int iz = v / (IY * IX); int r = v - iz * (IY * IX);
      int iy = r / IX; int ix = r - iy * IX;
      int gz = z0 + iz, gy = y0 + iy, gx = x0 + ix;
      float4 val = make_float4(0.f, 0.f, 0.f, 0.f);
      if (gz < Zi && gy < Yi && gx < Xi)
        val = *(const float4*)(inb + (size_t)((gz * Yi + gy) * Xi + gx) * 32 + h * 16 + q * 4);
      sin4[q][v] = val;
    }
    __syncthreads();
#pragma unroll 1
    for (int tap = 0; tap < 64; ++tap) {
      int kz = tap >> 4, ky = (tap >> 2) & 3, kx = tap & 3;
      int lv = ((oz + kz) * IY + (oy + ky)) * IX + (ox + kx);
      float4 a0 = sin4[0][lv];
      float4 a1 = sin4[1][lv];
      float4 a2 = sin4[2][lv];
      float4 a3 = sin4[3][lv];
      float4 w0 = wsh[tap * 8 + h * 4 + 0];
      float4 w1 = wsh[tap * 8 + h * 4 + 1];
      float4 w2 = wsh[tap * 8 + h * 4 + 2];
      float4 w3 = wsh[tap * 8 + h * 4 + 3];
      acc += a0.x*w0.x + a0.y*w0.y + a0.z*w0.z + a0.w*w0.w
           + a1.x*w1.x + a1.y*w1.y + a1.z*w1.z + a1.w*w1.w
           + a2.x*w2.x + a2.y*w2.y + a2.z*w2.z + a2.w*w2.w
           + a3.x*w3.x + a3.y*w3.y + a3.z*w3.z + a3.w*w3.w;
    }
  }

  int gz = z0 + oz, gy = y0 + oy, gx = x0 + ox;
  if (gz < Zo && gy < Yo && gx < Xo) {
    int ov = item * perOut + (gz * Yo + gy) * Xo + gx;
    bool act = mo[ov] > 0.f;
    out[ov] = act ? lrelu(acc + bias[0]) : NINF;
  }
}

// ---------------- pool z-walk (C=32, float4/thread, rotating 5-window) ---------
__global__ void k_pool_zw(const float* __restrict__ in, float* __restrict__ out,
                          int Zi, int Yi, int Xi, int Zo, int nI) {
  int gid = blockIdx.x * blockDim.x + threadIdx.x;
  int nCh = (Zo + PCZ - 1) / PCZ;
  int perI = nCh * Yi * Xi * 8;
  if (gid >= nI * perI) return;
  int c4 = gid & 7; int t = gid >> 3;
  int x = t % Xi; t /= Xi;
  int y = t % Yi; t /= Yi;
  int ch = t % nCh; int item = t / nCh;
  int z0 = ch * PCZ;
  int zend = z0 + PCZ; if (zend > Zo) zend = Zo;

  const float* colp = in + ((size_t)((item * Zi) * Yi + y) * Xi + x) * 32 + c4 * 4;
  const size_t zs = (size_t)Yi * Xi * 32;
  float* ocolp = out + ((size_t)((item * Zo) * Yi + y) * Xi + x) * 32 + c4 * 4;

  float4 w0 = *(const float4*)(colp + (size_t)(z0 + 0) * zs);
  float4 w1 = *(const float4*)(colp + (size_t)(z0 + 1) * zs);
  float4 w2 = *(const float4*)(colp + (size_t)(z0 + 2) * zs);
  float4 w3 = *(const float4*)(colp + (size_t)(z0 + 3) * zs);
#pragma unroll 2
  for (int z = z0; z < zend; ++z) {
    float4 c = *(const float4*)(colp + (size_t)(z + 4) * zs);
    float4 m = max4(max4(w0, w1), max4(w2, max4(w3, c)));
    *(float4*)(ocolp + (size_t)z * zs) = m;
    w0 = w1; w1 = w2; w2 = w3; w3 = c;
  }
}

// ---------------- pool y-walk (C=32, float4/thread, rotating 5-window) ---------
// maskless; in (Z,Yi,Xi) -> out (Z,Yo,Xi), Yo=Yi-4.
__global__ void k_pool_yw(const float* __restrict__ in, float* __restrict__ out,
                          int Z, int Yi, int Xi, int Yo, int nI) {
  int gid = blockIdx.x * blockDim.x + threadIdx.x;
  int nCh = (Yo + PCZ - 1) / PCZ;
  int perI = Z * nCh * Xi * 8;
  if (gid >= nI * perI) return;
  int c4 = gid & 7; int t = gid >> 3;
  int x = t % Xi; t /= Xi;
  int ch = t % nCh; t /= nCh;
  int z = t % Z; int item = t / Z;
  int y0 = ch * PCZ;
  int yend = y0 + PCZ; if (yend > Yo) yend = Yo;

  const float* colp = in + ((size_t)((item * Z + z) * Yi) * Xi + x) * 32 + c4 * 4;
  const size_t ys = (size_t)Xi * 32;
  float* ocolp = out + ((size_t)((item * Z + z) * Yo) * Xi + x) * 32 + c4 * 4;

  float4 w0 = *(const float4*)(colp + (size_t)(y0 + 0) * ys);
  float4 w1 = *(const float4*)(colp + (size_t)(y0 + 1) * ys);
  float4 w2 = *(const float4*)(colp + (size_t)(y0 + 2) * ys);
  float4 w3 = *(const float4*)(colp + (size_t)(y0 + 3) * ys);
#pragma unroll 2
  for (int y = y0; y < yend; ++y) {
    float4 c = *(const float4*)(colp + (size_t)(y + 4) * ys);
    float4 m = max4(max4(w0, w1), max4(w2, max4(w3, c)));
    *(float4*)(ocolp + (size_t)y * ys) = m;
    w0 = w1; w1 = w2; w2 = w3; w3 = c;
  }
}

// ---------------- pool x-walk (C=32, float4/thread, window-5) + mp gate --------
// in (Z,Yo,Xi) -> out (Z,Yo,Xo), Xo=Xi-4; gated by mp (per-voxel).
__global__ void k_pool_xw(const float* __restrict__ in, const float* __restrict__ mp,
                          float* __restrict__ out,
                          int Z, int Yo, int Xi, int Xo, int nI) {
  int gid = blockIdx.x * blockDim.x + threadIdx.x;
  int nCh = (Xo + PCZ - 1) / PCZ;
  int perI = Z * Yo * nCh * 8;
  if (gid >= nI * perI) return;
  int c4 = gid & 7; int t = gid >> 3;
  int ch = t % nCh; t /= nCh;
  int y = t % Yo; t /= Yo;
  int z = t % Z; int item = t / Z;
  int x0 = ch * PCZ;
  int xend = x0 + PCZ; if (xend > Xo) xend = Xo;

  const float* rowp = in + ((size_t)((item * Z + z) * Yo + y) * Xi) * 32 + c4 * 4;
  float* orowp = out + ((size_t)((item * Z + z) * Yo + y) * Xo) * 32 + c4 * 4;
  const float* mrow = mp + (size_t)item * Z * Yo * Xo + ((size_t)z * Yo + y) * Xo;

  float4 w0 = *(const float4*)(rowp + (size_t)(x0 + 0) * 32);
  float4 w1 = *(const float4*)(rowp + (size_t)(x0 + 1) * 32);
  float4 w2 = *(const float4*)(rowp + (size_t)(x0 + 2) * 32);
  float4 w3 = *(const float4*)(rowp + (size_t)(x0 + 3) * 32);
#pragma unroll 2
  for (int x = x0; x < xend; ++x) {
    float4 c = *(const float4*)(rowp + (size_t)(x + 4) * 32);
    float4 m = max4(max4(w0, w1), max4(w2, max4(w3, c)));
    bool act = mrow[x] > 0.f;
    float4 rv;
    rv.x = act ? m.x : 0.f; rv.y = act ? m.y : 0.f;
    rv.z = act ? m.z : 0.f; rv.w = act ? m.w : 0.f;
    *(float4*)(orowp + (size_t)x * 32) = rv;
    w0 = w1; w1 = w2; w2 = w3; w3 = c;
  }
}

// ---------------- final pool (C=1, direct 5^3), maskless via NINF sentinel ----
__global__ void k_pool3(const float* __restrict__ xin,
                        const float* __restrict__ mp, float* __restrict__ out, int nI) {
  int gid = blockIdx.x * blockDim.x + threadIdx.x;
  int perOut = 17 * 27 * 32;
  int tot = nI * perOut;
  if (gid >= tot) return;
  int item = gid / perOut;
  int r = gid - item * perOut;
  int x = r & 31; int t = r >> 5;
  int y = t % 27; int z = t / 27;
  const float* xb = xin + (size_t)item * 23436;
  float acc = NINF;
  for (int dz = 0; dz < 5; dz++)
    for (int dy = 0; dy < 5; dy++) {
      const float* rowx = xb + (size_t)(((z + dz)*31 + y + dy)*36 + x);
      for (int dx = 0; dx < 5; dx++)
        acc = fmaxf(acc, rowx[dx]);
    }
  out[gid] = (mp[gid] > 0.f) ? acc : 0.f;
}

// ---------------- FC split-K partial + finalize ----------------
__global__ __launch_bounds__(256, 4)
void k_fc_part(const float* __restrict__ X, const float* __restrict__ Wm,
               float* __restrict__ part, int K, int Ncol, int Kc) {
  __shared__ float sm[16][16][8];
  int ks = blockIdx.y;
  int k0 = ks * Kc;
  int k1 = k0 + Kc; if (k1 > K) k1 = K;
  int cl = threadIdx.x & 15;
  int kt = threadIdx.x >> 4;
  int col = blockIdx.x * 16 + cl;
  float a0=0.f,a1=0.f,a2=0.f,a3=0.f,a4=0.f,a5=0.f,a6=0.f,a7=0.f;
  if (col < Ncol) {
    for (int k = k0 + kt; k < k1; k += 16) {
      float w = Wm[(size_t)k * Ncol + col];
      a0 += X[0 * K + k] * w; a1 += X[1 * K + k] * w;
      a2 += X[2 * K + k] * w; a3 += X[3 * K + k] * w;
      a4 += X[4 * K + k] * w; a5 += X[5 * K + k] * w;
      a6 += X[6 * K + k] * w; a7 += X[7 * K + k] * w;
    }
  }
  sm[kt][cl][0]=a0; sm[kt][cl][1]=a1; sm[kt][cl][2]=a2; sm[kt][cl][3]=a3;
  sm[kt][cl][4]=a4; sm[kt][cl][5]=a5; sm[kt][cl][6]=a6; sm[kt][cl][7]=a7;
  __syncthreads();
  if (threadIdx.x < 128) {
    int c = threadIdx.x & 15;
    int b = threadIdx.x >> 4;
    float s = 0.f;
#pragma unroll
    for (int k = 0; k < 16; k++) s += sm[k][c][b];
    int cc = blockIdx.x * 16 + c;
    if (cc < Ncol) part[((size_t)ks * 8 + b) * Ncol + cc] = s;
  }
}

__global__ void k_fc_fin(const float* __restrict__ part, int ns,
                         const float* __restrict__ bias, float* __restrict__ out, int Ncol) {
  int i = blockIdx.x * blockDim.x + threadIdx.x;
  if (i >= 8 * Ncol) return;
  int b = i / Ncol;
  int c = i - b * Ncol;
  float s = 0.f;
  for (int ks = 0; ks < ns; ks++) s += part[((size_t)ks * 8 + b) * Ncol + c];
  out[i] = lrelu(s + bias[c]);
}

// last FC (K=1000 -> 1), small
__global__ __launch_bounds__(256, 4)
void k_fc(const float* __restrict__ X, const float* __restrict__ Wm,
          const float* __restrict__ bias, float* __restrict__ out,
          int K, int Ncol) {
  __shared__ float sm[16][16][8];
  int cl = threadIdx.x & 15;
  int kt = threadIdx.x >> 4;
  int col = blockIdx.x * 16 + cl;
  float a0=0.f,a1=0.f,a2=0.f,a3=0.f,a4=0.f,a5=0.f,a6=0.f,a7=0.f;
  if (col < Ncol) {
    for (int k = kt; k < K; k += 16) {
      float w = Wm[(size_t)k * Ncol + col];
      a0 += X[0 * K + k] * w; a1 += X[1 * K + k] * w;
      a2 += X[2 * K + k] * w; a3 += X[3 * K + k] * w;
      a4 += X[4 * K + k] * w; a5 += X[5 * K + k] * w;
      a6 += X[6 * K + k] * w; a7 += X[7 * K + k] * w;
    }
  }
  sm[kt][cl][0]=a0; sm[kt][cl][1]=a1; sm[kt][cl][2]=a2; sm[kt][cl][3]=a3;
  sm[kt][cl][4]=a4; sm[kt][cl][5]=a5; sm[kt][cl][6]=a6; sm[kt][cl][7]=a7;
  __syncthreads();
  if (threadIdx.x < 128) {
    int c = threadIdx.x & 15;
    int b = threadIdx.x >> 4;
    float s = 0.f;
#pragma unroll
    for (int k = 0; k < 16; k++) s += sm[k][c][b];
    int cc = blockIdx.x * 16 + c;
    if (cc < Ncol) out[b * Ncol + cc] = lrelu(s + bias[cc]);
  }
}

// ---------------- host ----------------
static inline int G256(long long n) { return (int)((n + 255) / 256); }

extern "C" void kernel_launch(void* const* d_in, const int* in_sizes, int n_in,
                              void* d_out, int out_size, void* d_ws, size_t ws_size,
                              hipStream_t stream) {
  const float* feat  = (const float*)d_in[0];
  const int*   coors = (const int*)d_in[1];
  const float* w1 = (const float*)d_in[3];  const float* b1 = (const float*)d_in[4];
  const float* w2 = (const float*)d_in[5];  const float* b2 = (const float*)d_in[6];
  const float* w3 = (const float*)d_in[7];  const float* b3 = (const float*)d_in[8];
  const float* w4 = (const float*)d_in[9];  const float* b4 = (const float*)d_in[10];
  const float* w5 = (const float*)d_in[11]; const float* b5 = (const float*)d_in[12];
  const float* w6 = (const float*)d_in[13]; const float* b6 = (const float*)d_in[14];
  const float* w7 = (const float*)d_in[15]; const float* b7 = (const float*)d_in[16];
  const float* W8 = (const float*)d_in[17]; const float* b8 = (const float*)d_in[18];
  const float* W9 = (const float*)d_in[19]; const float* b9 = (const float*)d_in[20];
  const float* W10= (const float*)d_in[21]; const float* b10= (const float*)d_in[22];
  float* out = (float*)d_out;

  char* ws = (char*)d_ws;
  size_t off = 0;
  auto alloc = [&](size_t nfloats) -> float* {
    float* p = (float*)(ws + off);
    off += ((nfloats * 4 + 1023) / 1024) * 1024;
    return p;
  };

  // ---- fixed allocations ----
  float* x0  = alloc(1560000);
  float* m0  = alloc(1560000);
  float* m1  = alloc(8 * 166098);
  float* m2  = alloc(8 * 140184);
  float* mp1 = alloc(8 * 110000);
  float* m3  = alloc(8 * 90428);
  float* m4  = alloc(8 * 73304);
  float* mp2 = alloc(8 * 54000);
  float* m5  = alloc(8 * 41958);
  float* m6  = alloc(8 * 31824);
  float* m7  = alloc(8 * 23436);
  float* mp3 = alloc(8 * 14688);
  float* p3  = alloc(8 * 14688);
  float* dt1 = alloc(8 * 183300);   // dilation temp (z-pass out, max 47*57*65... safe upper)
  float* wr1 = alloc(2048);
  float* wr7 = alloc(2048);
  unsigned short* tb2 = (unsigned short*)alloc(131072);   // 5 contiguous 512 KB tables
  unsigned short* tb3 = (unsigned short*)alloc(131072);
  unsigned short* tb4 = (unsigned short*)alloc(131072);
  unsigned short* tb5 = (unsigned short*)alloc(131072);
  unsigned short* tb6 = (unsigned short*)alloc(131072);
  float* part= alloc(64000);
  float* h8  = alloc(8000);
  float* h9  = alloc(8000);
  size_t fixedOff = off;

  // ---- pick group size G from remaining workspace ----
  const size_t perItemAB = ((size_t)5315136*4 + 1023)/1024*1024
                         + ((size_t)4485888*4 + 1023)/1024*1024
                         + ((size_t)23436*4 + 1023)/1024*1024;
  int G = 0;
  for (int g : {8, 4, 2, 1})
    if (fixedOff + (size_t)g * perItemAB <= ws_size) { G = g; break; }
  if (G == 0) return;

  float* A  = alloc((size_t)G * 5315136);
  float* Bb = alloc((size_t)G * 4485888);
  float* x7 = alloc((size_t)G * 23436);
  unsigned* claim = (unsigned*)A;   // claim aliases A (dead before first conv use)
  (void)dt1;

  // ---- init ----
  hipMemsetAsync(claim, 0, 1560000 * 4, stream);
  // x0 and m0 are adjacent 1KB-padded allocations; zero both in one call.
  hipMemsetAsync(x0, 0, 6240256 + 6240000, stream);

  k_repack_all<<<dim3(128, 7), 256, 0, stream>>>(w2, w3, w4, w5, w6, w1, w7,
                                                 tb2, wr1, wr7);

  const int N = 80000;
  k_claim  <<<G256(N), 256, 0, stream>>>(coors, claim, N);
  k_scatter<<<G256(N), 256, 0, stream>>>(coors, feat, claim, x0, m0, N);

  // ---- fused separable mask dilations (one kernel per stage, 8 items) ----
  auto dil3 = [&](const float* src, float* dst,
                  int Zi, int Yi, int Xi, int Zo, int Yo, int Xo, int K) {
    int tz = (Zo + 3) / 4, ty = (Yo + 7) / 8, tx = (Xo + 31) / 32;
    if (K == 4)
      kd_fused<4><<<8 * tz * ty * tx, 256, 0, stream>>>(src, dst, Zi,Yi,Xi, Zo,Yo,Xo, tz,ty,tx);
    else
      kd_fused<5><<<8 * tz * ty * tx, 256, 0, stream>>>(src, dst, Zi,Yi,Xi, Zo,Yo,Xo, tz,ty,tx);
  };
  dil3(m0,  m1,  50,60,65, 47,57,62, 4);
  dil3(m1,  m2,  47,57,62, 44,54,59, 4);
  dil3(m2,  mp1, 44,54,59, 40,50,55, 5);
  dil3(mp1, m3,  40,50,55, 37,47,52, 4);
  dil3(m3,  m4,  37,47,52, 34,44,49, 4);
  dil3(m4,  mp2, 34,44,49, 30,40,45, 5);
  dil3(mp2, m5,  30,40,45, 27,37,42, 4);
  dil3(m5,  m6,  27,37,42, 24,34,39, 4);
  dil3(m6,  m7,  24,34,39, 21,31,36, 4);
  dil3(m7,  mp3, 21,31,36, 17,27,32, 5);

  for (int g0 = 0; g0 < 8; g0 += G) {
    const float* x0g  = x0  + (size_t)g0 * 195000;
    const float* m1g  = m1  + (size_t)g0 * 166098;
    const float* m2g  = m2  + (size_t)g0 * 140184;
    const float* mp1g = mp1 + (size_t)g0 * 110000;
    const float* m3g  = m3  + (size_t)g0 * 90428;
    const float* m4g  = m4  + (size_t)g0 * 73304;
    const float* mp2g = mp2 + (size_t)g0 * 54000;
    const float* m5g  = m5  + (size_t)g0 * 41958;
    const float* m6g  = m6  + (size_t)g0 * 31824;
    const float* m7g  = m7  + (size_t)g0 * 23436;
    const float* mp3g = mp3 + (size_t)g0 * 14688;

    // c1: 50,60,65 -> 47,57,62
    {
      int tz = (47 + TZ - 1) / TZ, ty = (57 + TY - 1) / TY, tx = (62 + TXT - 1) / TXT;
      k_conv1t<<<G * tz * ty * tx, 256, 0, stream>>>(
          x0g, wr1, b1, m1g, A, 50,60,65, 47,57,62, tz, ty, tx);
    }
    // c2 -> 44,54,59   tile (4,4,16); POOLOUT (feeds p1)
    launch_conv32<4,4,16,7,7,19,true>(stream, A, tb2, b2, m2g, Bb, 47,57,62, 44,54,59, G);
    // p1 -> 40,50,55  (z-walk Bb->A, y-walk A->Bb, x-walk Bb->A gated)
    {
      int nCh = (40 + PCZ - 1) / PCZ;
      k_pool_zw<<<G256((long long)G * nCh * 54 * 59 * 8), 256, 0, stream>>>(Bb, A, 44,54,59, 40, G);
      int nChY = (50 + PCZ - 1) / PCZ;
      k_pool_yw<<<G256((long long)G * 40 * nChY * 59 * 8), 256, 0, stream>>>(A, Bb, 40,54,59, 50, G);
      int nChX = (55 + PCZ - 1) / PCZ;
      k_pool_xw<<<G256((long long)G * 40 * 50 * nChX * 8), 256, 0, stream>>>(Bb, mp1g, A, 40,50,59, 55, G);
    }
    // c3 -> 37,47,52   tile (8,8,4)  (in A, out Bb)
    launch_conv32<8,8,4,11,11,7,false>(stream, A, tb3, b3, m3g, Bb, 40,50,55, 37,47,52, G);
    // c4 -> 34,44,49   tile (4,16,4); POOLOUT (in Bb, out A; feeds p2)
    launch_conv32<4,16,4,7,19,7,true>(stream, Bb, tb4, b4, m4g, A, 37,47,52, 34,44,49, G);
    // p2 -> 30,40,45  (z-walk A->Bb, y-walk Bb->A, x-walk A->Bb gated)
    {
      int nCh = (30 + PCZ - 1) / PCZ;
      k_pool_zw<<<G256((long long)G * nCh * 44 * 49 * 8), 256, 0, stream>>>(A, Bb, 34,44,49, 30, G);
      int nChY = (40 + PCZ - 1) / PCZ;
      k_pool_yw<<<G256((long long)G * 30 * nChY * 49 * 8), 256, 0, stream>>>(Bb, A, 30,44,49, 40, G);
      int nChX = (45 + PCZ - 1) / PCZ;
      k_pool_xw<<<G256((long long)G * 30 * 40 * nChX * 8), 256, 0, stream>>>(A, mp2g, Bb, 30,40,49, 45, G);
    }
    // c5 -> 27,37,42   tile (4,4,16)  (in Bb, out A)
    launch_conv32<4,4,16,7,7,19,false>(stream, Bb, tb5, b5, m5g, A, 30,40,45, 27,37,42, G);
    // c6 -> 24,34,39   tile (8,4,8)   (in A, out Bb)
    launch_conv32<8,4,8,11,7,11,false>(stream, A, tb6, b6, m6g, Bb, 27,37,42, 24,34,39, G);
    // c7 (32->1) -> 21,31,36  (NINF sentinel out, feeds p3)
    {
      int tz = (21 + TZ - 1) / TZ, ty = (31 + TY - 1) / TY, tx = (36 + TXT - 1) / TXT;
      k_conv7t<<<G * tz * ty * tx, 256, 0, stream>>>(
          Bb, wr7, b7, m7g, x7, 24,34,39, 21,31,36, tz, ty, tx);
    }
    // p3 -> 17,27,32  (maskless 5^3 + mp gate)
    k_pool3<<<G256((long long)G*14688), 256, 0, stream>>>(
        x7, mp3g, p3 + (size_t)g0 * 14688, G);
  }

  // ---- FC head ----
  k_fc_part<<<dim3(63, 8), 256, 0, stream>>>(p3, W8, part, 14688, 1000, 1836);
  k_fc_fin <<<G256(8000), 256, 0, stream>>>(part, 8, b8, h8, 1000);
  k_fc_part<<<dim3(63, 4), 256, 0, stream>>>(h8, W9, part, 1000, 1000, 250);
  k_fc_fin <<<G256(8000), 256, 0, stream>>>(part, 4, b9, h9, 1000);
  k_fc<<<1, 256, 0, stream>>>(h9, W10, b10, out, 1000, 1);
}